// Round 12
// baseline (611.815 us; speedup 1.0000x reference)
//
#include <hip/hip_runtime.h>
#include <hip/hip_bf16.h>

#define DEPTH   6
#define DIM     192
#define HEADS   12
#define DH      16
#define MLPD    768
#define SEQ     256
#define BATCH   32
#define ROWS    (BATCH*SEQ)   // 8192

typedef __attribute__((ext_vector_type(8))) short short8;
typedef __attribute__((ext_vector_type(4))) float f32x4;
typedef __attribute__((ext_vector_type(4))) _Float16 half4;
typedef __attribute__((ext_vector_type(8))) _Float16 half8;
typedef __hip_bfloat16 bf16_t;
typedef _Float16 f16_t;

__device__ __forceinline__ bf16_t f2b(float v){ return __float2bfloat16(v); }
__device__ __forceinline__ ushort f2u(float v){
    union{ bf16_t b; ushort u; } w; w.b = __float2bfloat16(v); return w.u;
}
__device__ __forceinline__ f16_t u2h(ushort u){ union{ ushort u; f16_t h; } w; w.u = u; return w.h; }
__device__ __forceinline__ ushort h2u(f16_t h){ union{ ushort u; f16_t h; } w; w.h = h; return w.u; }

// async global->LDS, 16B per lane. LDS dest = wave-uniform base + lane*16B.
__device__ __forceinline__ void async16(ushort* lds, const ushort* gp){
    __builtin_amdgcn_global_load_lds(
        (const __attribute__((address_space(1))) uint*)gp,
        (__attribute__((address_space(3))) uint*)lds, 16, 0, 0);
}

// ---------------- residual init ----------------
__global__ void copy_kernel(const float* __restrict__ x, float* __restrict__ xr, int n){
    int i = blockIdx.x*256 + threadIdx.x;
    if (i < n) xr[i] = x[i];
}

// ---------------- weight transpose-convert, ALL matrices in one launch ----------
// W[l][K][N] fp32 -> WT[l][N][K] bf16, 64x64 tiles
__device__ __forceinline__ void wt_tile(const float* __restrict__ W,
        ushort* __restrict__ WT, int K, int N, int l, int tx, int ty,
        int tid, ushort* T){
    const float* src = W + ((size_t)l*K + tx*64)*N + ty*64;
    ushort* dst = WT + ((size_t)l*N + ty*64)*K + tx*64;
    int r = tid >> 2, c4 = (tid & 3)*16;
    #pragma unroll
    for (int u=0; u<4; u++){
        float4 v = *(const float4*)(src + (size_t)r*N + c4 + u*4);
        T[(c4+u*4+0)*72 + r] = f2u(v.x);
        T[(c4+u*4+1)*72 + r] = f2u(v.y);
        T[(c4+u*4+2)*72 + r] = f2u(v.z);
        T[(c4+u*4+3)*72 + r] = f2u(v.w);
    }
    __syncthreads();
    int n = tid >> 2, k8 = (tid & 3)*16;
    #pragma unroll
    for (int u=0; u<2; u++)
        *(uint4*)(dst + (size_t)n*K + k8 + u*8) = *(uint4*)&T[n*72 + k8 + u*8];
}

__global__ __launch_bounds__(256) void wt_all(
        const float* __restrict__ Wq, const float* __restrict__ Wkv,
        const float* __restrict__ Wo, const float* __restrict__ W1,
        const float* __restrict__ W2,
        ushort* __restrict__ WqT, ushort* __restrict__ WkvT,
        ushort* __restrict__ WoT, ushort* __restrict__ W1T,
        ushort* __restrict__ W2T){
    __shared__ ushort T[64*72];
    int id = blockIdx.x, l = blockIdx.y, tid = threadIdx.x;
    if (id < 9)       wt_tile(Wq,  WqT,  192, 192, l, id/3,       id%3,       tid, T);
    else if (id < 27) wt_tile(Wkv, WkvT, 192, 384, l, (id-9)/6,   (id-9)%6,   tid, T);
    else if (id < 36) wt_tile(Wo,  WoT,  192, 192, l, (id-27)/3,  (id-27)%3,  tid, T);
    else if (id < 72) wt_tile(W1,  W1T,  192, 768, l, (id-36)/12, (id-36)%12, tid, T);
    else              wt_tile(W2,  W2T,  768, 192, l, (id-72)/3,  (id-72)%3,  tid, T);
}

// ---------------- standalone LayerNorm: xres(f32) -> bf16 [8192 x 192] ----------
// used for ln1 only (ln2 fused into attn epilogue)
__global__ __launch_bounds__(256) void ln_kernel(
        const float* __restrict__ xres, const float* __restrict__ ln_g,
        const float* __restrict__ ln_b, ushort* __restrict__ out){
    int lane = threadIdx.x & 63, w = threadIdx.x >> 6;
    int row = blockIdx.x*4 + w;
    const float* xr = xres + (size_t)row*DIM;
    float v0 = xr[lane], v1 = xr[lane+64], v2 = xr[lane+128];
    float s = v0+v1+v2;
    #pragma unroll
    for (int off=32; off; off>>=1) s += __shfl_xor(s, off, 64);
    float m = s*(1.0f/192.0f);
    float d0=v0-m, d1=v1-m, d2=v2-m;
    float q = d0*d0+d1*d1+d2*d2;
    #pragma unroll
    for (int off=32; off; off>>=1) q += __shfl_xor(q, off, 64);
    float inv = rsqrtf(q*(1.0f/192.0f) + 1e-5f);
    float g0 = ln_g[lane], g1 = ln_g[lane+64], g2 = ln_g[lane+128];
    float e0 = ln_b[lane], e1 = ln_b[lane+64], e2 = ln_b[lane+128];
    ushort* dst = out + (size_t)row*DIM;
    dst[lane]     = f2u(d0*inv*g0 + e0);
    dst[lane+64]  = f2u(d1*inv*g1 + e1);
    dst[lane+128] = f2u(d2*inv*g2 + e2);
}

// ---------------- QKV GEMM (pre-LN'd bf16 A), one 64x64 tile per block ------
// cols<192: qb (f16 stride 192); <384: kb (f16 stride 192);
// else V TRANSPOSED: vT[b][d][j] (packed 8B stores, j = row%256)
__global__ __launch_bounds__(256) void gemm_qkv_kernel(
        const ushort* __restrict__ Aln, const ushort* __restrict__ BT0,
        const ushort* __restrict__ BT1,
        f16_t* __restrict__ out0, f16_t* __restrict__ out1,
        f16_t* __restrict__ out2){
    __shared__ ushort As[6*2048];      // [c][64][32]
    __shared__ ushort Bs[6*2048];
    int tid = threadIdx.x, lane = tid & 63, w = tid >> 6;
    int bm = blockIdx.x*64;
    int bn = blockIdx.y*64;
    {
        const ushort* ap = Aln + (size_t)(bm + (tid>>2))*DIM + (tid&3)*8;
        const ushort* bt; int bnl;
        if (bn >= DIM){ bt = BT1; bnl = bn - DIM; }
        else { bt = BT0; bnl = bn; }
        const ushort* bp = bt + (size_t)(bnl + (tid>>2))*DIM + (tid&3)*8;
        #pragma unroll
        for (int c=0; c<6; c++){
            async16(&As[c*2048 + tid*8], ap + c*32);
            async16(&Bs[c*2048 + tid*8], bp + c*32);
        }
    }
    __syncthreads();   // drains asyncs
    int wrow = w >> 1, wcol = w & 1;
    int quad = lane >> 4, mr = lane & 15;
    f32x4 acc[2][2] = {};
    #pragma unroll
    for (int c = 0; c < 6; c++){
        short8 a0 = *(const short8*)&As[c*2048 + (wrow*32+mr)*32    + quad*8];
        short8 a1 = *(const short8*)&As[c*2048 + (wrow*32+16+mr)*32 + quad*8];
        short8 b0 = *(const short8*)&Bs[c*2048 + (wcol*32+mr)*32    + quad*8];
        short8 b1 = *(const short8*)&Bs[c*2048 + (wcol*32+16+mr)*32 + quad*8];
        acc[0][0] = __builtin_amdgcn_mfma_f32_16x16x32_bf16(a0, b0, acc[0][0], 0,0,0);
        acc[0][1] = __builtin_amdgcn_mfma_f32_16x16x32_bf16(a0, b1, acc[0][1], 0,0,0);
        acc[1][0] = __builtin_amdgcn_mfma_f32_16x16x32_bf16(a1, b0, acc[1][0], 0,0,0);
        acc[1][1] = __builtin_amdgcn_mfma_f32_16x16x32_bf16(a1, b1, acc[1][1], 0,0,0);
    }
    #pragma unroll
    for (int rr=0; rr<2; rr++){
        #pragma unroll
        for (int cc=0; cc<2; cc++){
            int col = bn + wcol*32 + cc*16 + mr;
            if (col < 2*DIM){
                f16_t* op = (col < DIM) ? (out0 + col) : (out1 + col - DIM);
                #pragma unroll
                for (int tt=0; tt<4; tt++){
                    int row = bm + wrow*32 + rr*16 + quad*4 + tt;
                    op[(size_t)row*DIM] = (f16_t)acc[rr][cc][tt];
                }
            } else {
                int d = col - 2*DIM;
                int row0 = bm + wrow*32 + rr*16 + quad*4;
                int bb = row0 >> 8, j0 = row0 & 255;
                half4 pk;
                #pragma unroll
                for (int tt=0; tt<4; tt++) pk[tt] = (f16_t)acc[rr][cc][tt];
                *(half4*)(out2 + (((size_t)(bb*DIM + d)) << 8) + j0) = pk;
            }
        }
    }
}

// ---------------- W1 GEMM + exact GELU -> fb bf16 (stride MLPD) ----------------
// grid (128, 12): R8's proven path, 1536 blocks.
__global__ __launch_bounds__(256) void gemm_w1_kernel(
        const ushort* __restrict__ Aln, const ushort* __restrict__ BT0,
        const float* __restrict__ bias, bf16_t* __restrict__ out0){
    __shared__ ushort As[6*2048];      // [c][64][32]
    __shared__ ushort Bs[6*2048];
    int tid = threadIdx.x, lane = tid & 63, w = tid >> 6;
    int bm = blockIdx.x*64;
    int bn = blockIdx.y*64;
    {
        const ushort* ap = Aln + (size_t)(bm + (tid>>2))*DIM + (tid&3)*8;
        const ushort* bp = BT0 + (size_t)(bn + (tid>>2))*DIM + (tid&3)*8;
        #pragma unroll
        for (int c=0; c<6; c++){
            async16(&As[c*2048 + tid*8], ap + c*32);
            async16(&Bs[c*2048 + tid*8], bp + c*32);
        }
    }
    __syncthreads();   // drains asyncs
    int wrow = w >> 1, wcol = w & 1;
    int quad = lane >> 4, mr = lane & 15;
    f32x4 acc[2][2] = {};
    #pragma unroll
    for (int c = 0; c < 6; c++){
        short8 a0 = *(const short8*)&As[c*2048 + (wrow*32+mr)*32    + quad*8];
        short8 a1 = *(const short8*)&As[c*2048 + (wrow*32+16+mr)*32 + quad*8];
        short8 b0 = *(const short8*)&Bs[c*2048 + (wcol*32+mr)*32    + quad*8];
        short8 b1 = *(const short8*)&Bs[c*2048 + (wcol*32+16+mr)*32 + quad*8];
        acc[0][0] = __builtin_amdgcn_mfma_f32_16x16x32_bf16(a0, b0, acc[0][0], 0,0,0);
        acc[0][1] = __builtin_amdgcn_mfma_f32_16x16x32_bf16(a0, b1, acc[0][1], 0,0,0);
        acc[1][0] = __builtin_amdgcn_mfma_f32_16x16x32_bf16(a1, b0, acc[1][0], 0,0,0);
        acc[1][1] = __builtin_amdgcn_mfma_f32_16x16x32_bf16(a1, b1, acc[1][1], 0,0,0);
    }
    #pragma unroll
    for (int rr=0; rr<2; rr++){
        #pragma unroll
        for (int cc=0; cc<2; cc++){
            int col = bn + wcol*32 + cc*16 + mr;
            float bv = bias[col];
            #pragma unroll
            for (int tt=0; tt<4; tt++){
                int row = bm + wrow*32 + rr*16 + quad*4 + tt;
                float z = acc[rr][cc][tt] + bv;
                out0[(size_t)row*MLPD + col] =
                    f2b(0.5f*z*(1.0f + erff(z*0.70710678118654752f)));
            }
        }
    }
}

// ---------------- W2 GEMM + residual epilogue (R8 exact, non-atomic) -----------
template<int ROUNDS>
__global__ __launch_bounds__(256) void gemm_a_kernel(
        const ushort* __restrict__ A, const ushort* __restrict__ BT,
        const float* __restrict__ bias, const float* __restrict__ ls,
        float* __restrict__ xres){
    const int K = ROUNDS*192;
    __shared__ ushort As[6*2048];
    __shared__ ushort Bs[6*2048];
    int tid = threadIdx.x, lane = tid & 63, w = tid >> 6;
    int wrow = w >> 1, wcol = w & 1;
    int bm = blockIdx.x*64, bn = blockIdx.y*64;
    int quad = lane >> 4, mr = lane & 15;
    const ushort* ap = A  + (size_t)(bm + (tid>>2))*K + (tid&3)*8;
    const ushort* bp = BT + (size_t)(bn + (tid>>2))*K + (tid&3)*8;
    f32x4 acc[2][2] = {};
    for (int r = 0; r < ROUNDS; r++){
        #pragma unroll
        for (int c=0; c<6; c++){
            async16(&As[c*2048 + tid*8], ap + r*192 + c*32);
            async16(&Bs[c*2048 + tid*8], bp + r*192 + c*32);
        }
        __syncthreads();
        #pragma unroll
        for (int c=0; c<6; c++){
            short8 a0 = *(const short8*)&As[c*2048 + (wrow*32+mr)*32    + quad*8];
            short8 a1 = *(const short8*)&As[c*2048 + (wrow*32+16+mr)*32 + quad*8];
            short8 b0 = *(const short8*)&Bs[c*2048 + (wcol*32+mr)*32    + quad*8];
            short8 b1 = *(const short8*)&Bs[c*2048 + (wcol*32+16+mr)*32 + quad*8];
            acc[0][0] = __builtin_amdgcn_mfma_f32_16x16x32_bf16(a0, b0, acc[0][0], 0,0,0);
            acc[0][1] = __builtin_amdgcn_mfma_f32_16x16x32_bf16(a0, b1, acc[0][1], 0,0,0);
            acc[1][0] = __builtin_amdgcn_mfma_f32_16x16x32_bf16(a1, b0, acc[1][0], 0,0,0);
            acc[1][1] = __builtin_amdgcn_mfma_f32_16x16x32_bf16(a1, b1, acc[1][1], 0,0,0);
        }
        if (r+1 < ROUNDS) __syncthreads();
    }
    #pragma unroll
    for (int rr=0; rr<2; rr++){
        #pragma unroll
        for (int cc=0; cc<2; cc++){
            int col = bn + wcol*32 + cc*16 + mr;
            float bv = bias[col], lv = ls[col];
            #pragma unroll
            for (int tt=0; tt<4; tt++){
                int row = bm + wrow*32 + rr*16 + quad*4 + tt;
                xres[(size_t)row*DIM + col] += (acc[rr][cc][tt] + bv)*lv;
            }
        }
    }
}

// ------- fused attention + Wo + residual + LN2 (v15 = v14, latency-free tail) ---
// block = (batch, 16-row i-tile), 1024 threads / 16 waves, 512 blocks.
// v15 vs v14 (R11): the block owns rows [b*256+i0,+16) exclusively, so each
// wave PRELOADS its residual row at kernel start (coalesced; value unchanged
// until our own tail). Epilogue writes only delta=(wacc+bo)*ls1 to LDS X (no
// scattered global RMW). Tail: upd = preload + delta (same single f32 add ->
// bit-identical), coalesced xres row store, identical LN tree -> lnb.
#define SLAB    4488
#define IST     280
#define KV_OFF  53856          // 12*SLAB; VT chunk [192][72] lives here
#define VJP     72
#define ROWP    200
#define Q_OFF   67680          // KV_OFF + 192*72
#define POST_OFF 70880         // Q_OFF + 16*200
#define PRE_OFF 71136
#define X_OFF   71280          // f32[16][200] delta stash (ushort idx)
#define LTOT    77680          // 155,360 B

__global__ __launch_bounds__(1024, 1) void attn_kernel(
        const f16_t* __restrict__ qb, const f16_t* __restrict__ kb,
        const f16_t* __restrict__ vTg,
        const float* __restrict__ lsa, const float* __restrict__ pre,
        const float* __restrict__ post, const ushort* __restrict__ WoT,
        const float* __restrict__ bo, const float* __restrict__ ls1,
        const float* __restrict__ ln2g, const float* __restrict__ ln2b,
        ushort* __restrict__ lnb, float* __restrict__ xres){
    __shared__ ushort L[LTOT];
    int tid  = threadIdx.x;
    int lane = tid & 63, w = tid >> 6;      // w in [0,16)
    int quad = lane >> 4, nr = lane & 15;
    int b  = blockIdx.x >> 4;
    int i0 = (blockIdx.x & 15) << 4;

    // preload this wave's residual row (rows are block-exclusive; no writer
    // before our tail) — hides the tail's xres load under the whole kernel
    const float* xrow = xres + (size_t)(b*SEQ + i0 + w)*DIM;
    float xr0 = xrow[lane], xr1 = xrow[lane+64], xr2 = xrow[lane+128];

    auto stage_v = [&](int c){
        for (int u = tid; u < 1536; u += 1024){
            int e = u*8;
            int d = e >> 6, j = e & 63;
            uint4 v = *(const uint4*)(vTg + (((size_t)(b*DIM + d)) << 8) + c*64 + j);
            *(uint4*)&L[KV_OFF + d*VJP + j] = v;
        }
    };

    // stage Q (lsa folded) tid<384; postT self-zero-padded [384,512); pre [512,640)
    if (tid < 384){
        int e = tid*8, i = e/DIM, d = e%DIM, hh = d >> 4;
        float sc = lsa[hh];
        union { uint4 v; f16_t h[8]; } iv, ov;
        iv.v = *(const uint4*)(qb + (size_t)(b*SEQ + i0 + i)*DIM + d);
        #pragma unroll
        for (int u=0; u<8; u++) ov.h[u] = (f16_t)((float)iv.h[u]*sc);
        *(uint4*)&L[Q_OFF + i*ROWP + d] = ov.v;
    } else if (tid < 512){
        for (int k = tid-384; k < 256; k += 128){
            int gg = k >> 4, hh = k & 15;
            L[POST_OFF + k] = (gg < 12 && hh < 12) ? h2u((f16_t)post[hh*12+gg])
                                                   : (ushort)0;
        }
    } else if (tid < 640){
        for (int k = tid-512; k < 144; k += 128)
            L[PRE_OFF + k] = h2u((f16_t)pre[k]);
    }
    stage_v(0);
    __syncthreads();

    half4 postTf = *(const half4*)&L[POST_OFF + nr*16 + quad*4];

    // ---- P1+P2 factored: per g, full-K=192 MFMA with A-frag scaled by pre[h,g].
    {
        int jg = w*16 + nr;
        const f16_t* krow = kb + (size_t)(b*SEQ + jg)*DIM;
        half8 qh[6], kh[6];
        #pragma unroll
        for (int c=0; c<6; c++){
            union{ short8 s; half8 h; } a, k2;
            a.s  = *(const short8*)&L[Q_OFF + nr*ROWP + c*32 + quad*8];
            k2.s = *(const short8*)(const void*)(krow + c*32 + quad*8);
            qh[c] = a.h; kh[c] = k2.h;
        }
        int dd = jg - (i0 + quad*4);
        int hb = (quad>>1)*12;
        #pragma unroll
        for (int g=0; g<12; g++){
            f32x4 a = {0,0,0,0};
            #pragma unroll
            for (int c=0; c<6; c++){
                f16_t s = u2h(L[PRE_OFF + hb + c*24 + g]);
                a = __builtin_amdgcn_mfma_f32_16x16x32_f16(qh[c]*s, kh[c], a, 0,0,0);
            }
            ushort* sp = &L[g*SLAB + jg];
            sp[(quad*4+0)*IST] = (dd==0) ? (ushort)0 : h2u((f16_t)a[0]);
            sp[(quad*4+1)*IST] = (dd==1) ? (ushort)0 : h2u((f16_t)a[1]);
            sp[(quad*4+2)*IST] = (dd==2) ? (ushort)0 : h2u((f16_t)a[2]);
            sp[(quad*4+3)*IST] = (dd==3) ? (ushort)0 : h2u((f16_t)a[3]);
        }
    }
    __syncthreads();

    // ---- softmax over j: 12 rows per wave ----
    for (int r = w; r < 192; r += 16){
        int g = r >> 4, i = r & 15;
        ushort* sp = &L[g*SLAB + i*IST];
        ushort4 uv = *(ushort4*)&sp[lane*4];
        float e0 = __expf((float)u2h(uv.x));
        float e1 = __expf((float)u2h(uv.y));
        float e2 = __expf((float)u2h(uv.z));
        float e3 = __expf((float)u2h(uv.w));
        float ssum = e0+e1+e2+e3;
        #pragma unroll
        for (int off=32; off; off>>=1) ssum += __shfl_xor(ssum, off, 64);
        float rin = 1.0f/ssum;
        uv.x = h2u((f16_t)(e0*rin)); uv.y = h2u((f16_t)(e1*rin));
        uv.z = h2u((f16_t)(e2*rin)); uv.w = h2u((f16_t)(e3*rin));
        *(ushort4*)&sp[lane*4] = uv;
    }
    __syncthreads();

    // ---- P3: mix_post via MFMA, in-place; h>=12 reads clamped (postT zeros) ----
    for (int s = 0; s < 16; s++){
        int cb = s*16 + w;
        int i = cb >> 4, jb = cb & 15;
        int colbase = i*IST + jb*16 + nr;
        half4 bv;
        #pragma unroll
        for (int t=0; t<4; t++){
            int hs = quad*4 + t; if (hs > 11) hs = 11;
            bv[t] = u2h(L[hs*SLAB + colbase]);
        }
        f32x4 cc = __builtin_amdgcn_mfma_f32_16x16x16f16(postTf, bv, (f32x4){0,0,0,0}, 0,0,0);
        if (quad < 3){
            #pragma unroll
            for (int t=0; t<4; t++) L[(quad*4+t)*SLAB + colbase] = h2u((f16_t)cc[t]);
        }
    }
    __syncthreads();   // P3 done; chunk-0 V visible

    // ---- P4: O = P @ V; compute -> sync -> stage(c+1) -> sync ----
    f32x4 oacc = {0,0,0,0};
    for (int c = 0; c < 4; c++){
        if (w < 12){
            int g = w;
            #pragma unroll
            for (int ks = 0; ks < 4; ks++){
                int jl = ks*16 + quad*4;
                half4 av = *(const half4*)&L[g*SLAB + nr*IST + c*64 + jl];
                half4 bv = *(const half4*)&L[KV_OFF + (g*16 + nr)*VJP + jl];
                oacc = __builtin_amdgcn_mfma_f32_16x16x16f16(av, bv, oacc, 0,0,0);
            }
        }
        if (c < 3){
            __syncthreads();
            stage_v(c+1);
            __syncthreads();
        }
    }

    // ---- O (bf16) into Q region ----
    if (w < 12){
        int g = w;
        #pragma unroll
        for (int t=0; t<4; t++){
            int i = quad*4 + t;
            L[Q_OFF + i*ROWP + g*16 + nr] = f2u(oacc[t]);
        }
    }
    __syncthreads();

    // ---- O @ Wo: wave w < 12 owns col-tile w; delta -> X stash only ----
    float* X = (float*)&L[X_OFF];
    if (w < 12){
        f32x4 wacc = {0,0,0,0};
        int ct = w;
        const ushort* wg = WoT + (size_t)(ct*16 + nr)*192;
        #pragma unroll
        for (int c = 0; c < 3; c++){
            #pragma unroll
            for (int sub = 0; sub < 2; sub++){
                int k0 = c*64 + sub*32;
                short8 av = *(const short8*)&L[Q_OFF + nr*ROWP + k0 + quad*8];
                short8 bv = *(const short8*)(wg + k0 + quad*8);
                wacc = __builtin_amdgcn_mfma_f32_16x16x32_bf16(av, bv, wacc, 0,0,0);
            }
        }
        int col = ct*16 + nr;
        float bv2 = bo[col], lv = ls1[col];
        #pragma unroll
        for (int t=0; t<4; t++){
            int i = quad*4 + t;
            X[i*200 + col] = (wacc[t] + bv2)*lv;    // delta only — no global RMW
        }
    }
    __syncthreads();   // X visible

    // ---- tail: wave w owns row w: upd = preload + delta (bit-identical add);
    //      coalesced xres store; identical LN tree -> lnb ----
    {
        int i = w;
        float v0 = xr0 + X[i*200 + lane];
        float v1 = xr1 + X[i*200 + lane+64];
        float v2 = xr2 + X[i*200 + lane+128];
        float* xw = xres + (size_t)(b*SEQ + i0 + i)*DIM;
        xw[lane] = v0; xw[lane+64] = v1; xw[lane+128] = v2;
        float s = v0+v1+v2;
        #pragma unroll
        for (int off=32; off; off>>=1) s += __shfl_xor(s, off, 64);
        float m = s*(1.0f/192.0f);
        float d0=v0-m, d1=v1-m, d2=v2-m;
        float q = d0*d0+d1*d1+d2*d2;
        #pragma unroll
        for (int off=32; off; off>>=1) q += __shfl_xor(q, off, 64);
        float inv = rsqrtf(q*(1.0f/192.0f) + 1e-5f);
        float g0 = ln2g[lane], g1 = ln2g[lane+64], g2 = ln2g[lane+128];
        float e0 = ln2b[lane], e1 = ln2b[lane+64], e2 = ln2b[lane+128];
        ushort* dst = lnb + (size_t)(b*SEQ + i0 + i)*DIM;
        dst[lane]     = f2u(d0*inv*g0 + e0);
        dst[lane+64]  = f2u(d1*inv*g1 + e1);
        dst[lane+128] = f2u(d2*inv*g2 + e2);
    }
}

extern "C" void kernel_launch(void* const* d_in, const int* in_sizes, int n_in,
                              void* d_out, int out_size, void* d_ws, size_t ws_size,
                              hipStream_t stream){
    const float* x    = (const float*)d_in[0];
    const float* ln1g = (const float*)d_in[1];
    const float* ln1b = (const float*)d_in[2];
    const float* Wq   = (const float*)d_in[3];
    const float* Wkv  = (const float*)d_in[4];
    const float* lsa  = (const float*)d_in[5];
    const float* pre  = (const float*)d_in[6];
    const float* post = (const float*)d_in[7];
    const float* Wo   = (const float*)d_in[8];
    const float* bo   = (const float*)d_in[9];
    const float* ls1  = (const float*)d_in[10];
    const float* ln2g = (const float*)d_in[11];
    const float* ln2b = (const float*)d_in[12];
    const float* W1   = (const float*)d_in[13];
    const float* b1   = (const float*)d_in[14];
    const float* W2   = (const float*)d_in[15];
    const float* b2   = (const float*)d_in[16];
    const float* ls2  = (const float*)d_in[17];
    float* xres = (float*)d_out;             // fp32 residual lives in d_out

    char* ws = (char*)d_ws;
    // union region: qb+kb+vT (QKV->attn) overlaps fb (W1->W2) — disjoint lifetimes
    f16_t*  qb  = (f16_t*)ws;
    f16_t*  kb  = (f16_t*)(ws + (size_t)ROWS*DIM*2);
    f16_t*  vT  = (f16_t*)(ws + (size_t)ROWS*DIM*4);   // [B][192][256] f16
    bf16_t* fb  = (bf16_t*)ws;
    char* p = ws + (size_t)ROWS*MLPD*2;
    ushort* WqT  = (ushort*)p; p += (size_t)DEPTH*DIM*DIM*2;
    ushort* WkvT = (ushort*)p; p += (size_t)DEPTH*DIM*2*DIM*2;
    ushort* WoT  = (ushort*)p; p += (size_t)DEPTH*DIM*DIM*2;
    ushort* W1T  = (ushort*)p; p += (size_t)DEPTH*DIM*MLPD*2;
    ushort* W2T  = (ushort*)p; p += (size_t)DEPTH*MLPD*DIM*2;
    ushort* lnb  = (ushort*)p; p += (size_t)ROWS*DIM*2;   // pre-LN'd activations

    int ntot = ROWS*DIM;
    copy_kernel<<<ntot/256, 256, 0, stream>>>(x, xres, ntot);
    wt_all<<<dim3(108, 6), 256, 0, stream>>>(Wq, Wkv, Wo, W1, W2,
                                             WqT, WkvT, WoT, W1T, W2T);
    for (int l = 0; l < DEPTH; l++){
        ln_kernel<<<ROWS/4, 256, 0, stream>>>(xres, ln1g + l*DIM, ln1b + l*DIM, lnb);
        gemm_qkv_kernel<<<dim3(128,9), 256, 0, stream>>>(lnb,
                WqT + (size_t)l*DIM*DIM, WkvT + (size_t)l*DIM*2*DIM,
                qb, kb, vT);
        attn_kernel<<<BATCH*(SEQ/16), 1024, 0, stream>>>(qb, kb, vT,
                lsa + l*HEADS, pre + l*HEADS*HEADS, post + l*HEADS*HEADS,
                WoT + (size_t)l*DIM*DIM, bo + l*DIM, ls1 + l*DIM,
                ln2g + l*DIM, ln2b + l*DIM, lnb, xres);
        gemm_w1_kernel<<<dim3(128,12), 256, 0, stream>>>(lnb,
                W1T + (size_t)l*DIM*MLPD, b1 + l*MLPD, fb);
        gemm_a_kernel<4><<<dim3(128,3), 256, 0, stream>>>((const ushort*)fb,
                W2T + (size_t)l*MLPD*DIM, b2 + l*DIM, ls2 + l*DIM, xres);
    }
}

// Round 13
// 597.372 us; speedup vs baseline: 1.0242x; 1.0242x over previous
//
#include <hip/hip_runtime.h>
#include <hip/hip_bf16.h>

#define DEPTH   6
#define DIM     192
#define HEADS   12
#define DH      16
#define MLPD    768
#define SEQ     256
#define BATCH   32
#define ROWS    (BATCH*SEQ)   // 8192

typedef __attribute__((ext_vector_type(8))) short short8;
typedef __attribute__((ext_vector_type(4))) float f32x4;
typedef __attribute__((ext_vector_type(4))) _Float16 half4;
typedef __attribute__((ext_vector_type(8))) _Float16 half8;
typedef __hip_bfloat16 bf16_t;
typedef _Float16 f16_t;

__device__ __forceinline__ bf16_t f2b(float v){ return __float2bfloat16(v); }
__device__ __forceinline__ ushort f2u(float v){
    union{ bf16_t b; ushort u; } w; w.b = __float2bfloat16(v); return w.u;
}
__device__ __forceinline__ f16_t u2h(ushort u){ union{ ushort u; f16_t h; } w; w.u = u; return w.h; }
__device__ __forceinline__ ushort h2u(f16_t h){ union{ ushort u; f16_t h; } w; w.h = h; return w.u; }

// async global->LDS, 16B per lane. LDS dest = wave-uniform base + lane*16B.
__device__ __forceinline__ void async16(ushort* lds, const ushort* gp){
    __builtin_amdgcn_global_load_lds(
        (const __attribute__((address_space(1))) uint*)gp,
        (__attribute__((address_space(3))) uint*)lds, 16, 0, 0);
}

// ---------------- residual init ----------------
__global__ void copy_kernel(const float* __restrict__ x, float* __restrict__ xr, int n){
    int i = blockIdx.x*256 + threadIdx.x;
    if (i < n) xr[i] = x[i];
}

// ---------------- weight transpose-convert, ALL matrices in one launch ----------
// W[l][K][N] fp32 -> WT[l][N][K] bf16, 64x64 tiles
__device__ __forceinline__ void wt_tile(const float* __restrict__ W,
        ushort* __restrict__ WT, int K, int N, int l, int tx, int ty,
        int tid, ushort* T){
    const float* src = W + ((size_t)l*K + tx*64)*N + ty*64;
    ushort* dst = WT + ((size_t)l*N + ty*64)*K + tx*64;
    int r = tid >> 2, c4 = (tid & 3)*16;
    #pragma unroll
    for (int u=0; u<4; u++){
        float4 v = *(const float4*)(src + (size_t)r*N + c4 + u*4);
        T[(c4+u*4+0)*72 + r] = f2u(v.x);
        T[(c4+u*4+1)*72 + r] = f2u(v.y);
        T[(c4+u*4+2)*72 + r] = f2u(v.z);
        T[(c4+u*4+3)*72 + r] = f2u(v.w);
    }
    __syncthreads();
    int n = tid >> 2, k8 = (tid & 3)*16;
    #pragma unroll
    for (int u=0; u<2; u++)
        *(uint4*)(dst + (size_t)n*K + k8 + u*8) = *(uint4*)&T[n*72 + k8 + u*8];
}

__global__ __launch_bounds__(256) void wt_all(
        const float* __restrict__ Wq, const float* __restrict__ Wkv,
        const float* __restrict__ Wo, const float* __restrict__ W1,
        const float* __restrict__ W2,
        ushort* __restrict__ WqT, ushort* __restrict__ WkvT,
        ushort* __restrict__ WoT, ushort* __restrict__ W1T,
        ushort* __restrict__ W2T){
    __shared__ ushort T[64*72];
    int id = blockIdx.x, l = blockIdx.y, tid = threadIdx.x;
    if (id < 9)       wt_tile(Wq,  WqT,  192, 192, l, id/3,       id%3,       tid, T);
    else if (id < 27) wt_tile(Wkv, WkvT, 192, 384, l, (id-9)/6,   (id-9)%6,   tid, T);
    else if (id < 36) wt_tile(Wo,  WoT,  192, 192, l, (id-27)/3,  (id-27)%3,  tid, T);
    else if (id < 72) wt_tile(W1,  W1T,  192, 768, l, (id-36)/12, (id-36)%12, tid, T);
    else              wt_tile(W2,  W2T,  768, 192, l, (id-72)/3,  (id-72)%3,  tid, T);
}

// ---------------- standalone LayerNorm: xres(f32) -> bf16 [8192 x 192] ----------
// used for ln1 only (ln2 fused into attn epilogue)
__global__ __launch_bounds__(256) void ln_kernel(
        const float* __restrict__ xres, const float* __restrict__ ln_g,
        const float* __restrict__ ln_b, ushort* __restrict__ out){
    int lane = threadIdx.x & 63, w = threadIdx.x >> 6;
    int row = blockIdx.x*4 + w;
    const float* xr = xres + (size_t)row*DIM;
    float v0 = xr[lane], v1 = xr[lane+64], v2 = xr[lane+128];
    float s = v0+v1+v2;
    #pragma unroll
    for (int off=32; off; off>>=1) s += __shfl_xor(s, off, 64);
    float m = s*(1.0f/192.0f);
    float d0=v0-m, d1=v1-m, d2=v2-m;
    float q = d0*d0+d1*d1+d2*d2;
    #pragma unroll
    for (int off=32; off; off>>=1) q += __shfl_xor(q, off, 64);
    float inv = rsqrtf(q*(1.0f/192.0f) + 1e-5f);
    float g0 = ln_g[lane], g1 = ln_g[lane+64], g2 = ln_g[lane+128];
    float e0 = ln_b[lane], e1 = ln_b[lane+64], e2 = ln_b[lane+128];
    ushort* dst = out + (size_t)row*DIM;
    dst[lane]     = f2u(d0*inv*g0 + e0);
    dst[lane+64]  = f2u(d1*inv*g1 + e1);
    dst[lane+128] = f2u(d2*inv*g2 + e2);
}

// ---------------- QKV GEMM (pre-LN'd bf16 A), one 64x64 tile per block ------
// cols<192: qb (f16 stride 192); <384: kb (f16 stride 192);
// else V TRANSPOSED: vT[b][d][j] (packed 8B stores, j = row%256)
__global__ __launch_bounds__(256) void gemm_qkv_kernel(
        const ushort* __restrict__ Aln, const ushort* __restrict__ BT0,
        const ushort* __restrict__ BT1,
        f16_t* __restrict__ out0, f16_t* __restrict__ out1,
        f16_t* __restrict__ out2){
    __shared__ ushort As[6*2048];      // [c][64][32]
    __shared__ ushort Bs[6*2048];
    int tid = threadIdx.x, lane = tid & 63, w = tid >> 6;
    int bm = blockIdx.x*64;
    int bn = blockIdx.y*64;
    {
        const ushort* ap = Aln + (size_t)(bm + (tid>>2))*DIM + (tid&3)*8;
        const ushort* bt; int bnl;
        if (bn >= DIM){ bt = BT1; bnl = bn - DIM; }
        else { bt = BT0; bnl = bn; }
        const ushort* bp = bt + (size_t)(bnl + (tid>>2))*DIM + (tid&3)*8;
        #pragma unroll
        for (int c=0; c<6; c++){
            async16(&As[c*2048 + tid*8], ap + c*32);
            async16(&Bs[c*2048 + tid*8], bp + c*32);
        }
    }
    __syncthreads();   // drains asyncs
    int wrow = w >> 1, wcol = w & 1;
    int quad = lane >> 4, mr = lane & 15;
    f32x4 acc[2][2] = {};
    #pragma unroll
    for (int c = 0; c < 6; c++){
        short8 a0 = *(const short8*)&As[c*2048 + (wrow*32+mr)*32    + quad*8];
        short8 a1 = *(const short8*)&As[c*2048 + (wrow*32+16+mr)*32 + quad*8];
        short8 b0 = *(const short8*)&Bs[c*2048 + (wcol*32+mr)*32    + quad*8];
        short8 b1 = *(const short8*)&Bs[c*2048 + (wcol*32+16+mr)*32 + quad*8];
        acc[0][0] = __builtin_amdgcn_mfma_f32_16x16x32_bf16(a0, b0, acc[0][0], 0,0,0);
        acc[0][1] = __builtin_amdgcn_mfma_f32_16x16x32_bf16(a0, b1, acc[0][1], 0,0,0);
        acc[1][0] = __builtin_amdgcn_mfma_f32_16x16x32_bf16(a1, b0, acc[1][0], 0,0,0);
        acc[1][1] = __builtin_amdgcn_mfma_f32_16x16x32_bf16(a1, b1, acc[1][1], 0,0,0);
    }
    #pragma unroll
    for (int rr=0; rr<2; rr++){
        #pragma unroll
        for (int cc=0; cc<2; cc++){
            int col = bn + wcol*32 + cc*16 + mr;
            if (col < 2*DIM){
                f16_t* op = (col < DIM) ? (out0 + col) : (out1 + col - DIM);
                #pragma unroll
                for (int tt=0; tt<4; tt++){
                    int row = bm + wrow*32 + rr*16 + quad*4 + tt;
                    op[(size_t)row*DIM] = (f16_t)acc[rr][cc][tt];
                }
            } else {
                int d = col - 2*DIM;
                int row0 = bm + wrow*32 + rr*16 + quad*4;
                int bb = row0 >> 8, j0 = row0 & 255;
                half4 pk;
                #pragma unroll
                for (int tt=0; tt<4; tt++) pk[tt] = (f16_t)acc[rr][cc][tt];
                *(half4*)(out2 + (((size_t)(bb*DIM + d)) << 8) + j0) = pk;
            }
        }
    }
}

// ---------------- W1 GEMM + exact GELU -> fb bf16 (stride MLPD) ----------------
// grid (128, 12): R8's proven path, 1536 blocks.
__global__ __launch_bounds__(256) void gemm_w1_kernel(
        const ushort* __restrict__ Aln, const ushort* __restrict__ BT0,
        const float* __restrict__ bias, bf16_t* __restrict__ out0){
    __shared__ ushort As[6*2048];      // [c][64][32]
    __shared__ ushort Bs[6*2048];
    int tid = threadIdx.x, lane = tid & 63, w = tid >> 6;
    int bm = blockIdx.x*64;
    int bn = blockIdx.y*64;
    {
        const ushort* ap = Aln + (size_t)(bm + (tid>>2))*DIM + (tid&3)*8;
        const ushort* bp = BT0 + (size_t)(bn + (tid>>2))*DIM + (tid&3)*8;
        #pragma unroll
        for (int c=0; c<6; c++){
            async16(&As[c*2048 + tid*8], ap + c*32);
            async16(&Bs[c*2048 + tid*8], bp + c*32);
        }
    }
    __syncthreads();   // drains asyncs
    int wrow = w >> 1, wcol = w & 1;
    int quad = lane >> 4, mr = lane & 15;
    f32x4 acc[2][2] = {};
    #pragma unroll
    for (int c = 0; c < 6; c++){
        short8 a0 = *(const short8*)&As[c*2048 + (wrow*32+mr)*32    + quad*8];
        short8 a1 = *(const short8*)&As[c*2048 + (wrow*32+16+mr)*32 + quad*8];
        short8 b0 = *(const short8*)&Bs[c*2048 + (wcol*32+mr)*32    + quad*8];
        short8 b1 = *(const short8*)&Bs[c*2048 + (wcol*32+16+mr)*32 + quad*8];
        acc[0][0] = __builtin_amdgcn_mfma_f32_16x16x32_bf16(a0, b0, acc[0][0], 0,0,0);
        acc[0][1] = __builtin_amdgcn_mfma_f32_16x16x32_bf16(a0, b1, acc[0][1], 0,0,0);
        acc[1][0] = __builtin_amdgcn_mfma_f32_16x16x32_bf16(a1, b0, acc[1][0], 0,0,0);
        acc[1][1] = __builtin_amdgcn_mfma_f32_16x16x32_bf16(a1, b1, acc[1][1], 0,0,0);
    }
    #pragma unroll
    for (int rr=0; rr<2; rr++){
        #pragma unroll
        for (int cc=0; cc<2; cc++){
            int col = bn + wcol*32 + cc*16 + mr;
            float bv = bias[col];
            #pragma unroll
            for (int tt=0; tt<4; tt++){
                int row = bm + wrow*32 + rr*16 + quad*4 + tt;
                float z = acc[rr][cc][tt] + bv;
                out0[(size_t)row*MLPD + col] =
                    f2b(0.5f*z*(1.0f + erff(z*0.70710678118654752f)));
            }
        }
    }
}

// ---------------- W2 GEMM + residual epilogue (32-col tiles, balanced grid) ----
// grid (128, 6) = 768 blocks = 3/CU balanced (was (128,3)=384 -> half-idle
// round 2). LDS 36KB -> 4 blocks/CU capacity. Per-output K-chain (4 rounds x
// 6 c ascending, same fragments) bit-identical to the old kernel; only the
// wave->tile assignment changed.
__global__ __launch_bounds__(256) void gemm_a_kernel(
        const ushort* __restrict__ A, const ushort* __restrict__ BT,
        const float* __restrict__ bias, const float* __restrict__ ls,
        float* __restrict__ xres){
    const int K = 768;
    __shared__ ushort As[6*2048];      // [c][64][32]
    __shared__ ushort Bs[3*2048];      // [c][32][32]
    int tid = threadIdx.x, lane = tid & 63, w = tid >> 6;   // 4 waves
    int bm = blockIdx.x*64, bn = blockIdx.y*32;
    int quad = lane >> 4, mr = lane & 15;
    int wr = w >> 1, ct = w & 1;       // wave: rows wr*32+{0,16}, cols ct*16
    const ushort* ap = A + (size_t)(bm + (tid>>2))*K + (tid&3)*8;
    f32x4 acc[2] = {};
    for (int r = 0; r < 4; r++){
        #pragma unroll
        for (int c=0; c<6; c++)
            async16(&As[c*2048 + tid*8], ap + r*192 + c*32);
        #pragma unroll
        for (int p=0; p<3; p++){
            int u = p*256 + tid;
            int c = u >> 7, rem = u & 127;
            int rw = rem >> 2, k8 = rem & 3;
            async16(&Bs[u*8], BT + (size_t)(bn + rw)*K + r*192 + c*32 + k8*8);
        }
        __syncthreads();
        #pragma unroll
        for (int c=0; c<6; c++){
            short8 a0 = *(const short8*)&As[c*2048 + (wr*32+mr)*32    + quad*8];
            short8 a1 = *(const short8*)&As[c*2048 + (wr*32+16+mr)*32 + quad*8];
            short8 bv = *(const short8*)&Bs[c*1024 + (ct*16+mr)*32    + quad*8];
            acc[0] = __builtin_amdgcn_mfma_f32_16x16x32_bf16(a0, bv, acc[0], 0,0,0);
            acc[1] = __builtin_amdgcn_mfma_f32_16x16x32_bf16(a1, bv, acc[1], 0,0,0);
        }
        if (r < 3) __syncthreads();
    }
    #pragma unroll
    for (int rr=0; rr<2; rr++){
        int col = bn + ct*16 + mr;
        float bv = bias[col], lv = ls[col];
        #pragma unroll
        for (int tt=0; tt<4; tt++){
            int row = bm + wr*32 + rr*16 + quad*4 + tt;
            xres[(size_t)row*DIM + col] += (acc[rr][tt] + bv)*lv;
        }
    }
}

// ------- fused attention + Wo + residual + LN2 (v15, counter-verified 53.9us) ---
#define SLAB    4488
#define IST     280
#define KV_OFF  53856          // 12*SLAB; VT chunk [192][72] lives here
#define VJP     72
#define ROWP    200
#define Q_OFF   67680          // KV_OFF + 192*72
#define POST_OFF 70880         // Q_OFF + 16*200
#define PRE_OFF 71136
#define X_OFF   71280          // f32[16][200] delta stash (ushort idx)
#define LTOT    77680          // 155,360 B

__global__ __launch_bounds__(1024, 1) void attn_kernel(
        const f16_t* __restrict__ qb, const f16_t* __restrict__ kb,
        const f16_t* __restrict__ vTg,
        const float* __restrict__ lsa, const float* __restrict__ pre,
        const float* __restrict__ post, const ushort* __restrict__ WoT,
        const float* __restrict__ bo, const float* __restrict__ ls1,
        const float* __restrict__ ln2g, const float* __restrict__ ln2b,
        ushort* __restrict__ lnb, float* __restrict__ xres){
    __shared__ ushort L[LTOT];
    int tid  = threadIdx.x;
    int lane = tid & 63, w = tid >> 6;      // w in [0,16)
    int quad = lane >> 4, nr = lane & 15;
    int b  = blockIdx.x >> 4;
    int i0 = (blockIdx.x & 15) << 4;

    // preload this wave's residual row (rows are block-exclusive; no writer
    // before our tail) — hides the tail's xres load under the whole kernel
    const float* xrow = xres + (size_t)(b*SEQ + i0 + w)*DIM;
    float xr0 = xrow[lane], xr1 = xrow[lane+64], xr2 = xrow[lane+128];

    auto stage_v = [&](int c){
        for (int u = tid; u < 1536; u += 1024){
            int e = u*8;
            int d = e >> 6, j = e & 63;
            uint4 v = *(const uint4*)(vTg + (((size_t)(b*DIM + d)) << 8) + c*64 + j);
            *(uint4*)&L[KV_OFF + d*VJP + j] = v;
        }
    };

    // stage Q (lsa folded) tid<384; postT self-zero-padded [384,512); pre [512,640)
    if (tid < 384){
        int e = tid*8, i = e/DIM, d = e%DIM, hh = d >> 4;
        float sc = lsa[hh];
        union { uint4 v; f16_t h[8]; } iv, ov;
        iv.v = *(const uint4*)(qb + (size_t)(b*SEQ + i0 + i)*DIM + d);
        #pragma unroll
        for (int u=0; u<8; u++) ov.h[u] = (f16_t)((float)iv.h[u]*sc);
        *(uint4*)&L[Q_OFF + i*ROWP + d] = ov.v;
    } else if (tid < 512){
        for (int k = tid-384; k < 256; k += 128){
            int gg = k >> 4, hh = k & 15;
            L[POST_OFF + k] = (gg < 12 && hh < 12) ? h2u((f16_t)post[hh*12+gg])
                                                   : (ushort)0;
        }
    } else if (tid < 640){
        for (int k = tid-512; k < 144; k += 128)
            L[PRE_OFF + k] = h2u((f16_t)pre[k]);
    }
    stage_v(0);
    __syncthreads();

    half4 postTf = *(const half4*)&L[POST_OFF + nr*16 + quad*4];

    // ---- P1+P2 factored: per g, full-K=192 MFMA with A-frag scaled by pre[h,g].
    {
        int jg = w*16 + nr;
        const f16_t* krow = kb + (size_t)(b*SEQ + jg)*DIM;
        half8 qh[6], kh[6];
        #pragma unroll
        for (int c=0; c<6; c++){
            union{ short8 s; half8 h; } a, k2;
            a.s  = *(const short8*)&L[Q_OFF + nr*ROWP + c*32 + quad*8];
            k2.s = *(const short8*)(const void*)(krow + c*32 + quad*8);
            qh[c] = a.h; kh[c] = k2.h;
        }
        int dd = jg - (i0 + quad*4);
        int hb = (quad>>1)*12;
        #pragma unroll
        for (int g=0; g<12; g++){
            f32x4 a = {0,0,0,0};
            #pragma unroll
            for (int c=0; c<6; c++){
                f16_t s = u2h(L[PRE_OFF + hb + c*24 + g]);
                a = __builtin_amdgcn_mfma_f32_16x16x32_f16(qh[c]*s, kh[c], a, 0,0,0);
            }
            ushort* sp = &L[g*SLAB + jg];
            sp[(quad*4+0)*IST] = (dd==0) ? (ushort)0 : h2u((f16_t)a[0]);
            sp[(quad*4+1)*IST] = (dd==1) ? (ushort)0 : h2u((f16_t)a[1]);
            sp[(quad*4+2)*IST] = (dd==2) ? (ushort)0 : h2u((f16_t)a[2]);
            sp[(quad*4+3)*IST] = (dd==3) ? (ushort)0 : h2u((f16_t)a[3]);
        }
    }
    __syncthreads();

    // ---- softmax over j: 12 rows per wave ----
    for (int r = w; r < 192; r += 16){
        int g = r >> 4, i = r & 15;
        ushort* sp = &L[g*SLAB + i*IST];
        ushort4 uv = *(ushort4*)&sp[lane*4];
        float e0 = __expf((float)u2h(uv.x));
        float e1 = __expf((float)u2h(uv.y));
        float e2 = __expf((float)u2h(uv.z));
        float e3 = __expf((float)u2h(uv.w));
        float ssum = e0+e1+e2+e3;
        #pragma unroll
        for (int off=32; off; off>>=1) ssum += __shfl_xor(ssum, off, 64);
        float rin = 1.0f/ssum;
        uv.x = h2u((f16_t)(e0*rin)); uv.y = h2u((f16_t)(e1*rin));
        uv.z = h2u((f16_t)(e2*rin)); uv.w = h2u((f16_t)(e3*rin));
        *(ushort4*)&sp[lane*4] = uv;
    }
    __syncthreads();

    // ---- P3: mix_post via MFMA, in-place; h>=12 reads clamped (postT zeros) ----
    for (int s = 0; s < 16; s++){
        int cb = s*16 + w;
        int i = cb >> 4, jb = cb & 15;
        int colbase = i*IST + jb*16 + nr;
        half4 bv;
        #pragma unroll
        for (int t=0; t<4; t++){
            int hs = quad*4 + t; if (hs > 11) hs = 11;
            bv[t] = u2h(L[hs*SLAB + colbase]);
        }
        f32x4 cc = __builtin_amdgcn_mfma_f32_16x16x16f16(postTf, bv, (f32x4){0,0,0,0}, 0,0,0);
        if (quad < 3){
            #pragma unroll
            for (int t=0; t<4; t++) L[(quad*4+t)*SLAB + colbase] = h2u((f16_t)cc[t]);
        }
    }
    __syncthreads();   // P3 done; chunk-0 V visible

    // ---- P4: O = P @ V; compute -> sync -> stage(c+1) -> sync ----
    f32x4 oacc = {0,0,0,0};
    for (int c = 0; c < 4; c++){
        if (w < 12){
            int g = w;
            #pragma unroll
            for (int ks = 0; ks < 4; ks++){
                int jl = ks*16 + quad*4;
                half4 av = *(const half4*)&L[g*SLAB + nr*IST + c*64 + jl];
                half4 bv = *(const half4*)&L[KV_OFF + (g*16 + nr)*VJP + jl];
                oacc = __builtin_amdgcn_mfma_f32_16x16x16f16(av, bv, oacc, 0,0,0);
            }
        }
        if (c < 3){
            __syncthreads();
            stage_v(c+1);
            __syncthreads();
        }
    }

    // ---- O (bf16) into Q region ----
    if (w < 12){
        int g = w;
        #pragma unroll
        for (int t=0; t<4; t++){
            int i = quad*4 + t;
            L[Q_OFF + i*ROWP + g*16 + nr] = f2u(oacc[t]);
        }
    }
    __syncthreads();

    // ---- O @ Wo: wave w < 12 owns col-tile w; delta -> X stash only ----
    float* X = (float*)&L[X_OFF];
    if (w < 12){
        f32x4 wacc = {0,0,0,0};
        int ct = w;
        const ushort* wg = WoT + (size_t)(ct*16 + nr)*192;
        #pragma unroll
        for (int c = 0; c < 3; c++){
            #pragma unroll
            for (int sub = 0; sub < 2; sub++){
                int k0 = c*64 + sub*32;
                short8 av = *(const short8*)&L[Q_OFF + nr*ROWP + k0 + quad*8];
                short8 bv = *(const short8*)(wg + k0 + quad*8);
                wacc = __builtin_amdgcn_mfma_f32_16x16x32_bf16(av, bv, wacc, 0,0,0);
            }
        }
        int col = ct*16 + nr;
        float bv2 = bo[col], lv = ls1[col];
        #pragma unroll
        for (int t=0; t<4; t++){
            int i = quad*4 + t;
            X[i*200 + col] = (wacc[t] + bv2)*lv;    // delta only — no global RMW
        }
    }
    __syncthreads();   // X visible

    // ---- tail: wave w owns row w: upd = preload + delta (bit-identical add);
    //      coalesced xres store; identical LN tree -> lnb ----
    {
        int i = w;
        float v0 = xr0 + X[i*200 + lane];
        float v1 = xr1 + X[i*200 + lane+64];
        float v2 = xr2 + X[i*200 + lane+128];
        float* xw = xres + (size_t)(b*SEQ + i0 + i)*DIM;
        xw[lane] = v0; xw[lane+64] = v1; xw[lane+128] = v2;
        float s = v0+v1+v2;
        #pragma unroll
        for (int off=32; off; off>>=1) s += __shfl_xor(s, off, 64);
        float m = s*(1.0f/192.0f);
        float d0=v0-m, d1=v1-m, d2=v2-m;
        float q = d0*d0+d1*d1+d2*d2;
        #pragma unroll
        for (int off=32; off; off>>=1) q += __shfl_xor(q, off, 64);
        float inv = rsqrtf(q*(1.0f/192.0f) + 1e-5f);
        float g0 = ln2g[lane], g1 = ln2g[lane+64], g2 = ln2g[lane+128];
        float e0 = ln2b[lane], e1 = ln2b[lane+64], e2 = ln2b[lane+128];
        ushort* dst = lnb + (size_t)(b*SEQ + i0 + i)*DIM;
        dst[lane]     = f2u(d0*inv*g0 + e0);
        dst[lane+64]  = f2u(d1*inv*g1 + e1);
        dst[lane+128] = f2u(d2*inv*g2 + e2);
    }
}

extern "C" void kernel_launch(void* const* d_in, const int* in_sizes, int n_in,
                              void* d_out, int out_size, void* d_ws, size_t ws_size,
                              hipStream_t stream){
    const float* x    = (const float*)d_in[0];
    const float* ln1g = (const float*)d_in[1];
    const float* ln1b = (const float*)d_in[2];
    const float* Wq   = (const float*)d_in[3];
    const float* Wkv  = (const float*)d_in[4];
    const float* lsa  = (const float*)d_in[5];
    const float* pre  = (const float*)d_in[6];
    const float* post = (const float*)d_in[7];
    const float* Wo   = (const float*)d_in[8];
    const float* bo   = (const float*)d_in[9];
    const float* ls1  = (const float*)d_in[10];
    const float* ln2g = (const float*)d_in[11];
    const float* ln2b = (const float*)d_in[12];
    const float* W1   = (const float*)d_in[13];
    const float* b1   = (const float*)d_in[14];
    const float* W2   = (const float*)d_in[15];
    const float* b2   = (const float*)d_in[16];
    const float* ls2  = (const float*)d_in[17];
    float* xres = (float*)d_out;             // fp32 residual lives in d_out

    char* ws = (char*)d_ws;
    // union region: qb+kb+vT (QKV->attn) overlaps fb (W1->W2) — disjoint lifetimes
    f16_t*  qb  = (f16_t*)ws;
    f16_t*  kb  = (f16_t*)(ws + (size_t)ROWS*DIM*2);
    f16_t*  vT  = (f16_t*)(ws + (size_t)ROWS*DIM*4);   // [B][192][256] f16
    bf16_t* fb  = (bf16_t*)ws;
    char* p = ws + (size_t)ROWS*MLPD*2;
    ushort* WqT  = (ushort*)p; p += (size_t)DEPTH*DIM*DIM*2;
    ushort* WkvT = (ushort*)p; p += (size_t)DEPTH*DIM*2*DIM*2;
    ushort* WoT  = (ushort*)p; p += (size_t)DEPTH*DIM*DIM*2;
    ushort* W1T  = (ushort*)p; p += (size_t)DEPTH*DIM*MLPD*2;
    ushort* W2T  = (ushort*)p; p += (size_t)DEPTH*MLPD*DIM*2;
    ushort* lnb  = (ushort*)p; p += (size_t)ROWS*DIM*2;   // pre-LN'd activations

    int ntot = ROWS*DIM;
    copy_kernel<<<ntot/256, 256, 0, stream>>>(x, xres, ntot);
    wt_all<<<dim3(108, 6), 256, 0, stream>>>(Wq, Wkv, Wo, W1, W2,
                                             WqT, WkvT, WoT, W1T, W2T);
    for (int l = 0; l < DEPTH; l++){
        ln_kernel<<<ROWS/4, 256, 0, stream>>>(xres, ln1g + l*DIM, ln1b + l*DIM, lnb);
        gemm_qkv_kernel<<<dim3(128,9), 256, 0, stream>>>(lnb,
                WqT + (size_t)l*DIM*DIM, WkvT + (size_t)l*DIM*2*DIM,
                qb, kb, vT);
        attn_kernel<<<BATCH*(SEQ/16), 1024, 0, stream>>>(qb, kb, vT,
                lsa + l*HEADS, pre + l*HEADS*HEADS, post + l*HEADS*HEADS,
                WoT + (size_t)l*DIM*DIM, bo + l*DIM, ls1 + l*DIM,
                ln2g + l*DIM, ln2b + l*DIM, lnb, xres);
        gemm_w1_kernel<<<dim3(128,12), 256, 0, stream>>>(lnb,
                W1T + (size_t)l*DIM*MLPD, b1 + l*MLPD, fb);
        gemm_a_kernel<<<dim3(128,6), 256, 0, stream>>>((const ushort*)fb,
                W2T + (size_t)l*MLPD*DIM, b2 + l*DIM, ls2 + l*DIM, xres);
    }
}

// Round 14
// 582.902 us; speedup vs baseline: 1.0496x; 1.0248x over previous
//
#include <hip/hip_runtime.h>
#include <hip/hip_bf16.h>

#define DEPTH   6
#define DIM     192
#define HEADS   12
#define DH      16
#define MLPD    768
#define SEQ     256
#define BATCH   32
#define ROWS    (BATCH*SEQ)   // 8192

typedef __attribute__((ext_vector_type(8))) short short8;
typedef __attribute__((ext_vector_type(4))) float f32x4;
typedef __attribute__((ext_vector_type(4))) _Float16 half4;
typedef __attribute__((ext_vector_type(8))) _Float16 half8;
typedef __hip_bfloat16 bf16_t;
typedef _Float16 f16_t;

__device__ __forceinline__ bf16_t f2b(float v){ return __float2bfloat16(v); }
__device__ __forceinline__ ushort f2u(float v){
    union{ bf16_t b; ushort u; } w; w.b = __float2bfloat16(v); return w.u;
}
__device__ __forceinline__ f16_t u2h(ushort u){ union{ ushort u; f16_t h; } w; w.u = u; return w.h; }
__device__ __forceinline__ ushort h2u(f16_t h){ union{ ushort u; f16_t h; } w; w.h = h; return w.u; }

// async global->LDS, 16B per lane. LDS dest = wave-uniform base + lane*16B.
__device__ __forceinline__ void async16(ushort* lds, const ushort* gp){
    __builtin_amdgcn_global_load_lds(
        (const __attribute__((address_space(1))) uint*)gp,
        (__attribute__((address_space(3))) uint*)lds, 16, 0, 0);
}

// ---------------- residual init ----------------
__global__ void copy_kernel(const float* __restrict__ x, float* __restrict__ xr, int n){
    int i = blockIdx.x*256 + threadIdx.x;
    if (i < n) xr[i] = x[i];
}

// ---------------- weight transpose-convert, ALL matrices in one launch ----------
// W[l][K][N] fp32 -> WT[l][N][K] bf16, 64x64 tiles
__device__ __forceinline__ void wt_tile(const float* __restrict__ W,
        ushort* __restrict__ WT, int K, int N, int l, int tx, int ty,
        int tid, ushort* T){
    const float* src = W + ((size_t)l*K + tx*64)*N + ty*64;
    ushort* dst = WT + ((size_t)l*N + ty*64)*K + tx*64;
    int r = tid >> 2, c4 = (tid & 3)*16;
    #pragma unroll
    for (int u=0; u<4; u++){
        float4 v = *(const float4*)(src + (size_t)r*N + c4 + u*4);
        T[(c4+u*4+0)*72 + r] = f2u(v.x);
        T[(c4+u*4+1)*72 + r] = f2u(v.y);
        T[(c4+u*4+2)*72 + r] = f2u(v.z);
        T[(c4+u*4+3)*72 + r] = f2u(v.w);
    }
    __syncthreads();
    int n = tid >> 2, k8 = (tid & 3)*16;
    #pragma unroll
    for (int u=0; u<2; u++)
        *(uint4*)(dst + (size_t)n*K + k8 + u*8) = *(uint4*)&T[n*72 + k8 + u*8];
}

__global__ __launch_bounds__(256) void wt_all(
        const float* __restrict__ Wq, const float* __restrict__ Wkv,
        const float* __restrict__ Wo, const float* __restrict__ W1,
        const float* __restrict__ W2,
        ushort* __restrict__ WqT, ushort* __restrict__ WkvT,
        ushort* __restrict__ WoT, ushort* __restrict__ W1T,
        ushort* __restrict__ W2T){
    __shared__ ushort T[64*72];
    int id = blockIdx.x, l = blockIdx.y, tid = threadIdx.x;
    if (id < 9)       wt_tile(Wq,  WqT,  192, 192, l, id/3,       id%3,       tid, T);
    else if (id < 27) wt_tile(Wkv, WkvT, 192, 384, l, (id-9)/6,   (id-9)%6,   tid, T);
    else if (id < 36) wt_tile(Wo,  WoT,  192, 192, l, (id-27)/3,  (id-27)%3,  tid, T);
    else if (id < 72) wt_tile(W1,  W1T,  192, 768, l, (id-36)/12, (id-36)%12, tid, T);
    else              wt_tile(W2,  W2T,  768, 192, l, (id-72)/3,  (id-72)%3,  tid, T);
}

// ---------------- standalone LayerNorm: xres(f32) -> bf16 [8192 x 192] ----------
// used for ln1 only (ln2 fused into attn epilogue)
__global__ __launch_bounds__(256) void ln_kernel(
        const float* __restrict__ xres, const float* __restrict__ ln_g,
        const float* __restrict__ ln_b, ushort* __restrict__ out){
    int lane = threadIdx.x & 63, w = threadIdx.x >> 6;
    int row = blockIdx.x*4 + w;
    const float* xr = xres + (size_t)row*DIM;
    float v0 = xr[lane], v1 = xr[lane+64], v2 = xr[lane+128];
    float s = v0+v1+v2;
    #pragma unroll
    for (int off=32; off; off>>=1) s += __shfl_xor(s, off, 64);
    float m = s*(1.0f/192.0f);
    float d0=v0-m, d1=v1-m, d2=v2-m;
    float q = d0*d0+d1*d1+d2*d2;
    #pragma unroll
    for (int off=32; off; off>>=1) q += __shfl_xor(q, off, 64);
    float inv = rsqrtf(q*(1.0f/192.0f) + 1e-5f);
    float g0 = ln_g[lane], g1 = ln_g[lane+64], g2 = ln_g[lane+128];
    float e0 = ln_b[lane], e1 = ln_b[lane+64], e2 = ln_b[lane+128];
    ushort* dst = out + (size_t)row*DIM;
    dst[lane]     = f2u(d0*inv*g0 + e0);
    dst[lane+64]  = f2u(d1*inv*g1 + e1);
    dst[lane+128] = f2u(d2*inv*g2 + e2);
}

// ---------------- QKV GEMM (pre-LN'd bf16 A), one 64x64 tile per block ------
// cols<192: qb (f16 stride 192); <384: kb (f16 stride 192);
// else V TRANSPOSED: vT[b][d][j] (packed 8B stores, j = row%256)
__global__ __launch_bounds__(256) void gemm_qkv_kernel(
        const ushort* __restrict__ Aln, const ushort* __restrict__ BT0,
        const ushort* __restrict__ BT1,
        f16_t* __restrict__ out0, f16_t* __restrict__ out1,
        f16_t* __restrict__ out2){
    __shared__ ushort As[6*2048];      // [c][64][32]
    __shared__ ushort Bs[6*2048];
    int tid = threadIdx.x, lane = tid & 63, w = tid >> 6;
    int bm = blockIdx.x*64;
    int bn = blockIdx.y*64;
    {
        const ushort* ap = Aln + (size_t)(bm + (tid>>2))*DIM + (tid&3)*8;
        const ushort* bt; int bnl;
        if (bn >= DIM){ bt = BT1; bnl = bn - DIM; }
        else { bt = BT0; bnl = bn; }
        const ushort* bp = bt + (size_t)(bnl + (tid>>2))*DIM + (tid&3)*8;
        #pragma unroll
        for (int c=0; c<6; c++){
            async16(&As[c*2048 + tid*8], ap + c*32);
            async16(&Bs[c*2048 + tid*8], bp + c*32);
        }
    }
    __syncthreads();   // drains asyncs
    int wrow = w >> 1, wcol = w & 1;
    int quad = lane >> 4, mr = lane & 15;
    f32x4 acc[2][2] = {};
    #pragma unroll
    for (int c = 0; c < 6; c++){
        short8 a0 = *(const short8*)&As[c*2048 + (wrow*32+mr)*32    + quad*8];
        short8 a1 = *(const short8*)&As[c*2048 + (wrow*32+16+mr)*32 + quad*8];
        short8 b0 = *(const short8*)&Bs[c*2048 + (wcol*32+mr)*32    + quad*8];
        short8 b1 = *(const short8*)&Bs[c*2048 + (wcol*32+16+mr)*32 + quad*8];
        acc[0][0] = __builtin_amdgcn_mfma_f32_16x16x32_bf16(a0, b0, acc[0][0], 0,0,0);
        acc[0][1] = __builtin_amdgcn_mfma_f32_16x16x32_bf16(a0, b1, acc[0][1], 0,0,0);
        acc[1][0] = __builtin_amdgcn_mfma_f32_16x16x32_bf16(a1, b0, acc[1][0], 0,0,0);
        acc[1][1] = __builtin_amdgcn_mfma_f32_16x16x32_bf16(a1, b1, acc[1][1], 0,0,0);
    }
    #pragma unroll
    for (int rr=0; rr<2; rr++){
        #pragma unroll
        for (int cc=0; cc<2; cc++){
            int col = bn + wcol*32 + cc*16 + mr;
            if (col < 2*DIM){
                f16_t* op = (col < DIM) ? (out0 + col) : (out1 + col - DIM);
                #pragma unroll
                for (int tt=0; tt<4; tt++){
                    int row = bm + wrow*32 + rr*16 + quad*4 + tt;
                    op[(size_t)row*DIM] = (f16_t)acc[rr][cc][tt];
                }
            } else {
                int d = col - 2*DIM;
                int row0 = bm + wrow*32 + rr*16 + quad*4;
                int bb = row0 >> 8, j0 = row0 & 255;
                half4 pk;
                #pragma unroll
                for (int tt=0; tt<4; tt++) pk[tt] = (f16_t)acc[rr][cc][tt];
                *(half4*)(out2 + (((size_t)(bb*DIM + d)) << 8) + j0) = pk;
            }
        }
    }
}

// ---------------- W1 GEMM + exact GELU -> fb bf16 (stride MLPD) ----------------
// grid (128, 12): R8's proven path, 1536 blocks.
__global__ __launch_bounds__(256) void gemm_w1_kernel(
        const ushort* __restrict__ Aln, const ushort* __restrict__ BT0,
        const float* __restrict__ bias, bf16_t* __restrict__ out0){
    __shared__ ushort As[6*2048];      // [c][64][32]
    __shared__ ushort Bs[6*2048];
    int tid = threadIdx.x, lane = tid & 63, w = tid >> 6;
    int bm = blockIdx.x*64;
    int bn = blockIdx.y*64;
    {
        const ushort* ap = Aln + (size_t)(bm + (tid>>2))*DIM + (tid&3)*8;
        const ushort* bp = BT0 + (size_t)(bn + (tid>>2))*DIM + (tid&3)*8;
        #pragma unroll
        for (int c=0; c<6; c++){
            async16(&As[c*2048 + tid*8], ap + c*32);
            async16(&Bs[c*2048 + tid*8], bp + c*32);
        }
    }
    __syncthreads();   // drains asyncs
    int wrow = w >> 1, wcol = w & 1;
    int quad = lane >> 4, mr = lane & 15;
    f32x4 acc[2][2] = {};
    #pragma unroll
    for (int c = 0; c < 6; c++){
        short8 a0 = *(const short8*)&As[c*2048 + (wrow*32+mr)*32    + quad*8];
        short8 a1 = *(const short8*)&As[c*2048 + (wrow*32+16+mr)*32 + quad*8];
        short8 b0 = *(const short8*)&Bs[c*2048 + (wcol*32+mr)*32    + quad*8];
        short8 b1 = *(const short8*)&Bs[c*2048 + (wcol*32+16+mr)*32 + quad*8];
        acc[0][0] = __builtin_amdgcn_mfma_f32_16x16x32_bf16(a0, b0, acc[0][0], 0,0,0);
        acc[0][1] = __builtin_amdgcn_mfma_f32_16x16x32_bf16(a0, b1, acc[0][1], 0,0,0);
        acc[1][0] = __builtin_amdgcn_mfma_f32_16x16x32_bf16(a1, b0, acc[1][0], 0,0,0);
        acc[1][1] = __builtin_amdgcn_mfma_f32_16x16x32_bf16(a1, b1, acc[1][1], 0,0,0);
    }
    #pragma unroll
    for (int rr=0; rr<2; rr++){
        #pragma unroll
        for (int cc=0; cc<2; cc++){
            int col = bn + wcol*32 + cc*16 + mr;
            float bv = bias[col];
            #pragma unroll
            for (int tt=0; tt<4; tt++){
                int row = bm + wrow*32 + rr*16 + quad*4 + tt;
                float z = acc[rr][cc][tt] + bv;
                out0[(size_t)row*MLPD + col] =
                    f2b(0.5f*z*(1.0f + erff(z*0.70710678118654752f)));
            }
        }
    }
}

// ---------------- W2 GEMM + residual epilogue (32-col tiles, balanced grid) ----
// grid (128, 6) = 768 blocks = 3/CU balanced. K-chain bit-identical.
__global__ __launch_bounds__(256) void gemm_a_kernel(
        const ushort* __restrict__ A, const ushort* __restrict__ BT,
        const float* __restrict__ bias, const float* __restrict__ ls,
        float* __restrict__ xres){
    const int K = 768;
    __shared__ ushort As[6*2048];      // [c][64][32]
    __shared__ ushort Bs[3*2048];      // [c][32][32]
    int tid = threadIdx.x, lane = tid & 63, w = tid >> 6;   // 4 waves
    int bm = blockIdx.x*64, bn = blockIdx.y*32;
    int quad = lane >> 4, mr = lane & 15;
    int wr = w >> 1, ct = w & 1;       // wave: rows wr*32+{0,16}, cols ct*16
    const ushort* ap = A + (size_t)(bm + (tid>>2))*K + (tid&3)*8;
    f32x4 acc[2] = {};
    for (int r = 0; r < 4; r++){
        #pragma unroll
        for (int c=0; c<6; c++)
            async16(&As[c*2048 + tid*8], ap + r*192 + c*32);
        #pragma unroll
        for (int p=0; p<3; p++){
            int u = p*256 + tid;
            int c = u >> 7, rem = u & 127;
            int rw = rem >> 2, k8 = rem & 3;
            async16(&Bs[u*8], BT + (size_t)(bn + rw)*K + r*192 + c*32 + k8*8);
        }
        __syncthreads();
        #pragma unroll
        for (int c=0; c<6; c++){
            short8 a0 = *(const short8*)&As[c*2048 + (wr*32+mr)*32    + quad*8];
            short8 a1 = *(const short8*)&As[c*2048 + (wr*32+16+mr)*32 + quad*8];
            short8 bv = *(const short8*)&Bs[c*1024 + (ct*16+mr)*32    + quad*8];
            acc[0] = __builtin_amdgcn_mfma_f32_16x16x32_bf16(a0, bv, acc[0], 0,0,0);
            acc[1] = __builtin_amdgcn_mfma_f32_16x16x32_bf16(a1, bv, acc[1], 0,0,0);
        }
        if (r < 3) __syncthreads();
    }
    #pragma unroll
    for (int rr=0; rr<2; rr++){
        int col = bn + ct*16 + mr;
        float bv = bias[col], lv = ls[col];
        #pragma unroll
        for (int tt=0; tt<4; tt++){
            int row = bm + wr*32 + rr*16 + quad*4 + tt;
            xres[(size_t)row*DIM + col] += (acc[rr][tt] + bv)*lv;
        }
    }
}

// ------- fused attention + Wo + residual + LN2 (v16 = v15 + async-swizzled V) ---
// block = (batch, 16-row i-tile), 1024 threads / 16 waves, 512 blocks.
// v16 vs v15 (53.9us): V staged via global_load_lds (no VGPR round-trip).
// Linear LDS dest (VJP 72->64) + XOR swizzle applied BOTH sides (m173/rule21):
//   stage: lane u -> dest = KV_OFF + u*8 (linear); source col j = ((u&7)*8) ^
//          ((d&7)<<3) where d = u>>3 (pre-swizzled global address)
//   read:  physical j = jl ^ ((nr&7)<<3)  (same involution; 4-ushort aligned,
//          within one 8-ushort granule; rows spread 4 banks apart -> 2-way free)
// V bytes land permuted but are read through the inverse map -> bit-identical.
#define SLAB    4488
#define IST     280
#define KV_OFF  53856          // 12*SLAB; VT chunk [192][64] linear+swizzled
#define ROWP    200
#define Q_OFF   67680          // KV_OFF + 192*72 (1536 ushort slack after V)
#define POST_OFF 70880         // Q_OFF + 16*200
#define PRE_OFF 71136
#define X_OFF   71280          // f32[16][200] delta stash (ushort idx)
#define LTOT    77680          // 155,360 B

__global__ __launch_bounds__(1024, 1) void attn_kernel(
        const f16_t* __restrict__ qb, const f16_t* __restrict__ kb,
        const f16_t* __restrict__ vTg,
        const float* __restrict__ lsa, const float* __restrict__ pre,
        const float* __restrict__ post, const ushort* __restrict__ WoT,
        const float* __restrict__ bo, const float* __restrict__ ls1,
        const float* __restrict__ ln2g, const float* __restrict__ ln2b,
        ushort* __restrict__ lnb, float* __restrict__ xres){
    __shared__ ushort L[LTOT];
    int tid  = threadIdx.x;
    int lane = tid & 63, w = tid >> 6;      // w in [0,16)
    int quad = lane >> 4, nr = lane & 15;
    int b  = blockIdx.x >> 4;
    int i0 = (blockIdx.x & 15) << 4;

    // preload this wave's residual row (rows are block-exclusive; no writer
    // before our tail) — hides the tail's xres load under the whole kernel
    const float* xrow = xres + (size_t)(b*SEQ + i0 + w)*DIM;
    float xr0 = xrow[lane], xr1 = xrow[lane+64], xr2 = xrow[lane+128];

    // V chunk stage: async direct-to-LDS, linear dest, pre-swizzled source
    auto stage_v = [&](int c){
        for (int u = tid; u < 1536; u += 1024){
            int d   = u >> 3;
            int jsw = ((u & 7)*8) ^ ((d & 7) << 3);
            async16(&L[KV_OFF + u*8],
                    (const ushort*)(vTg + (((size_t)(b*DIM + d)) << 8) + c*64 + jsw));
        }
    };

    // stage Q (lsa folded) tid<384; postT self-zero-padded [384,512); pre [512,640)
    if (tid < 384){
        int e = tid*8, i = e/DIM, d = e%DIM, hh = d >> 4;
        float sc = lsa[hh];
        union { uint4 v; f16_t h[8]; } iv, ov;
        iv.v = *(const uint4*)(qb + (size_t)(b*SEQ + i0 + i)*DIM + d);
        #pragma unroll
        for (int u=0; u<8; u++) ov.h[u] = (f16_t)((float)iv.h[u]*sc);
        *(uint4*)&L[Q_OFF + i*ROWP + d] = ov.v;
    } else if (tid < 512){
        for (int k = tid-384; k < 256; k += 128){
            int gg = k >> 4, hh = k & 15;
            L[POST_OFF + k] = (gg < 12 && hh < 12) ? h2u((f16_t)post[hh*12+gg])
                                                   : (ushort)0;
        }
    } else if (tid < 640){
        for (int k = tid-512; k < 144; k += 128)
            L[PRE_OFF + k] = h2u((f16_t)pre[k]);
    }
    stage_v(0);
    __syncthreads();

    half4 postTf = *(const half4*)&L[POST_OFF + nr*16 + quad*4];

    // ---- P1+P2 factored: per g, full-K=192 MFMA with A-frag scaled by pre[h,g].
    {
        int jg = w*16 + nr;
        const f16_t* krow = kb + (size_t)(b*SEQ + jg)*DIM;
        half8 qh[6], kh[6];
        #pragma unroll
        for (int c=0; c<6; c++){
            union{ short8 s; half8 h; } a, k2;
            a.s  = *(const short8*)&L[Q_OFF + nr*ROWP + c*32 + quad*8];
            k2.s = *(const short8*)(const void*)(krow + c*32 + quad*8);
            qh[c] = a.h; kh[c] = k2.h;
        }
        int dd = jg - (i0 + quad*4);
        int hb = (quad>>1)*12;
        #pragma unroll
        for (int g=0; g<12; g++){
            f32x4 a = {0,0,0,0};
            #pragma unroll
            for (int c=0; c<6; c++){
                f16_t s = u2h(L[PRE_OFF + hb + c*24 + g]);
                a = __builtin_amdgcn_mfma_f32_16x16x32_f16(qh[c]*s, kh[c], a, 0,0,0);
            }
            ushort* sp = &L[g*SLAB + jg];
            sp[(quad*4+0)*IST] = (dd==0) ? (ushort)0 : h2u((f16_t)a[0]);
            sp[(quad*4+1)*IST] = (dd==1) ? (ushort)0 : h2u((f16_t)a[1]);
            sp[(quad*4+2)*IST] = (dd==2) ? (ushort)0 : h2u((f16_t)a[2]);
            sp[(quad*4+3)*IST] = (dd==3) ? (ushort)0 : h2u((f16_t)a[3]);
        }
    }
    __syncthreads();

    // ---- softmax over j: 12 rows per wave ----
    for (int r = w; r < 192; r += 16){
        int g = r >> 4, i = r & 15;
        ushort* sp = &L[g*SLAB + i*IST];
        ushort4 uv = *(ushort4*)&sp[lane*4];
        float e0 = __expf((float)u2h(uv.x));
        float e1 = __expf((float)u2h(uv.y));
        float e2 = __expf((float)u2h(uv.z));
        float e3 = __expf((float)u2h(uv.w));
        float ssum = e0+e1+e2+e3;
        #pragma unroll
        for (int off=32; off; off>>=1) ssum += __shfl_xor(ssum, off, 64);
        float rin = 1.0f/ssum;
        uv.x = h2u((f16_t)(e0*rin)); uv.y = h2u((f16_t)(e1*rin));
        uv.z = h2u((f16_t)(e2*rin)); uv.w = h2u((f16_t)(e3*rin));
        *(ushort4*)&sp[lane*4] = uv;
    }
    __syncthreads();

    // ---- P3: mix_post via MFMA, in-place; h>=12 reads clamped (postT zeros) ----
    for (int s = 0; s < 16; s++){
        int cb = s*16 + w;
        int i = cb >> 4, jb = cb & 15;
        int colbase = i*IST + jb*16 + nr;
        half4 bv;
        #pragma unroll
        for (int t=0; t<4; t++){
            int hs = quad*4 + t; if (hs > 11) hs = 11;
            bv[t] = u2h(L[hs*SLAB + colbase]);
        }
        f32x4 cc = __builtin_amdgcn_mfma_f32_16x16x16f16(postTf, bv, (f32x4){0,0,0,0}, 0,0,0);
        if (quad < 3){
            #pragma unroll
            for (int t=0; t<4; t++) L[(quad*4+t)*SLAB + colbase] = h2u((f16_t)cc[t]);
        }
    }
    __syncthreads();   // P3 done; chunk-0 V visible

    // ---- P4: O = P @ V; compute -> sync -> stage(c+1) -> sync ----
    f32x4 oacc = {0,0,0,0};
    for (int c = 0; c < 4; c++){
        if (w < 12){
            int g = w;
            int rsw = (nr & 7) << 3;           // per-row V swizzle
            #pragma unroll
            for (int ks = 0; ks < 4; ks++){
                int jl = ks*16 + quad*4;
                half4 av = *(const half4*)&L[g*SLAB + nr*IST + c*64 + jl];
                half4 bv = *(const half4*)&L[KV_OFF + (g*16 + nr)*64 + (jl ^ rsw)];
                oacc = __builtin_amdgcn_mfma_f32_16x16x16f16(av, bv, oacc, 0,0,0);
            }
        }
        if (c < 3){
            __syncthreads();
            stage_v(c+1);
            __syncthreads();
        }
    }

    // ---- O (bf16) into Q region ----
    if (w < 12){
        int g = w;
        #pragma unroll
        for (int t=0; t<4; t++){
            int i = quad*4 + t;
            L[Q_OFF + i*ROWP + g*16 + nr] = f2u(oacc[t]);
        }
    }
    __syncthreads();

    // ---- O @ Wo: wave w < 12 owns col-tile w; delta -> X stash only ----
    float* X = (float*)&L[X_OFF];
    if (w < 12){
        f32x4 wacc = {0,0,0,0};
        int ct = w;
        const ushort* wg = WoT + (size_t)(ct*16 + nr)*192;
        #pragma unroll
        for (int c = 0; c < 3; c++){
            #pragma unroll
            for (int sub = 0; sub < 2; sub++){
                int k0 = c*64 + sub*32;
                short8 av = *(const short8*)&L[Q_OFF + nr*ROWP + k0 + quad*8];
                short8 bv = *(const short8*)(wg + k0 + quad*8);
                wacc = __builtin_amdgcn_mfma_f32_16x16x32_bf16(av, bv, wacc, 0,0,0);
            }
        }
        int col = ct*16 + nr;
        float bv2 = bo[col], lv = ls1[col];
        #pragma unroll
        for (int t=0; t<4; t++){
            int i = quad*4 + t;
            X[i*200 + col] = (wacc[t] + bv2)*lv;    // delta only — no global RMW
        }
    }
    __syncthreads();   // X visible

    // ---- tail: wave w owns row w: upd = preload + delta (bit-identical add);
    //      coalesced xres store; identical LN tree -> lnb ----
    {
        int i = w;
        float v0 = xr0 + X[i*200 + lane];
        float v1 = xr1 + X[i*200 + lane+64];
        float v2 = xr2 + X[i*200 + lane+128];
        float* xw = xres + (size_t)(b*SEQ + i0 + i)*DIM;
        xw[lane] = v0; xw[lane+64] = v1; xw[lane+128] = v2;
        float s = v0+v1+v2;
        #pragma unroll
        for (int off=32; off; off>>=1) s += __shfl_xor(s, off, 64);
        float m = s*(1.0f/192.0f);
        float d0=v0-m, d1=v1-m, d2=v2-m;
        float q = d0*d0+d1*d1+d2*d2;
        #pragma unroll
        for (int off=32; off; off>>=1) q += __shfl_xor(q, off, 64);
        float inv = rsqrtf(q*(1.0f/192.0f) + 1e-5f);
        float g0 = ln2g[lane], g1 = ln2g[lane+64], g2 = ln2g[lane+128];
        float e0 = ln2b[lane], e1 = ln2b[lane+64], e2 = ln2b[lane+128];
        ushort* dst = lnb + (size_t)(b*SEQ + i0 + i)*DIM;
        dst[lane]     = f2u(d0*inv*g0 + e0);
        dst[lane+64]  = f2u(d1*inv*g1 + e1);
        dst[lane+128] = f2u(d2*inv*g2 + e2);
    }
}

extern "C" void kernel_launch(void* const* d_in, const int* in_sizes, int n_in,
                              void* d_out, int out_size, void* d_ws, size_t ws_size,
                              hipStream_t stream){
    const float* x    = (const float*)d_in[0];
    const float* ln1g = (const float*)d_in[1];
    const float* ln1b = (const float*)d_in[2];
    const float* Wq   = (const float*)d_in[3];
    const float* Wkv  = (const float*)d_in[4];
    const float* lsa  = (const float*)d_in[5];
    const float* pre  = (const float*)d_in[6];
    const float* post = (const float*)d_in[7];
    const float* Wo   = (const float*)d_in[8];
    const float* bo   = (const float*)d_in[9];
    const float* ls1  = (const float*)d_in[10];
    const float* ln2g = (const float*)d_in[11];
    const float* ln2b = (const float*)d_in[12];
    const float* W1   = (const float*)d_in[13];
    const float* b1   = (const float*)d_in[14];
    const float* W2   = (const float*)d_in[15];
    const float* b2   = (const float*)d_in[16];
    const float* ls2  = (const float*)d_in[17];
    float* xres = (float*)d_out;             // fp32 residual lives in d_out

    char* ws = (char*)d_ws;
    // union region: qb+kb+vT (QKV->attn) overlaps fb (W1->W2) — disjoint lifetimes
    f16_t*  qb  = (f16_t*)ws;
    f16_t*  kb  = (f16_t*)(ws + (size_t)ROWS*DIM*2);
    f16_t*  vT  = (f16_t*)(ws + (size_t)ROWS*DIM*4);   // [B][192][256] f16
    bf16_t* fb  = (bf16_t*)ws;
    char* p = ws + (size_t)ROWS*MLPD*2;
    ushort* WqT  = (ushort*)p; p += (size_t)DEPTH*DIM*DIM*2;
    ushort* WkvT = (ushort*)p; p += (size_t)DEPTH*DIM*2*DIM*2;
    ushort* WoT  = (ushort*)p; p += (size_t)DEPTH*DIM*DIM*2;
    ushort* W1T  = (ushort*)p; p += (size_t)DEPTH*DIM*MLPD*2;
    ushort* W2T  = (ushort*)p; p += (size_t)DEPTH*MLPD*DIM*2;
    ushort* lnb  = (ushort*)p; p += (size_t)ROWS*DIM*2;   // pre-LN'd activations

    int ntot = ROWS*DIM;
    copy_kernel<<<ntot/256, 256, 0, stream>>>(x, xres, ntot);
    wt_all<<<dim3(108, 6), 256, 0, stream>>>(Wq, Wkv, Wo, W1, W2,
                                             WqT, WkvT, WoT, W1T, W2T);
    for (int l = 0; l < DEPTH; l++){
        ln_kernel<<<ROWS/4, 256, 0, stream>>>(xres, ln1g + l*DIM, ln1b + l*DIM, lnb);
        gemm_qkv_kernel<<<dim3(128,9), 256, 0, stream>>>(lnb,
                WqT + (size_t)l*DIM*DIM, WkvT + (size_t)l*DIM*2*DIM,
                qb, kb, vT);
        attn_kernel<<<BATCH*(SEQ/16), 1024, 0, stream>>>(qb, kb, vT,
                lsa + l*HEADS, pre + l*HEADS*HEADS, post + l*HEADS*HEADS,
                WoT + (size_t)l*DIM*DIM, bo + l*DIM, ls1 + l*DIM,
                ln2g + l*DIM, ln2b + l*DIM, lnb, xres);
        gemm_w1_kernel<<<dim3(128,12), 256, 0, stream>>>(lnb,
                W1T + (size_t)l*DIM*MLPD, b1 + l*MLPD, fb);
        gemm_a_kernel<<<dim3(128,6), 256, 0, stream>>>((const ushort*)fb,
                W2T + (size_t)l*MLPD*DIM, b2 + l*DIM, ls2 + l*DIM, xres);
    }
}